// Round 6
// baseline (143.429 us; speedup 1.0000x reference)
//
#include <hip/hip_runtime.h>
#include <math.h>

typedef unsigned short ushort_t;
typedef __attribute__((ext_vector_type(8))) __bf16 bf16x8;
typedef __attribute__((ext_vector_type(4))) float floatx4;

#define B_    256
#define I_    1152
#define J_    10
#define DIN_  8
#define DOUT_ 16
#define K_    (I_*DIN_)     // 9216
#define N_    (J_*DOUT_)    // 160
#define KSPLIT 16           // total split-K per output tile
#define KCHUNK (K_/KSPLIT)  // 576 (72 i's per wave)
#define KSTEPS (KCHUNK/32)  // 18

// Padded pitches: de-alias the L2 channel interleave. x row stride was
// 9216*4 B = 144*256 B (== 0 mod 16 channels -> every lane same channel);
// +80 floats makes it an odd multiple of 64 B -> rows rotate channels.
#define XPITCH  9296        // 9216 + 80 floats (320 B pad)
#define WIPITCH 1360        // per-i W row: 1280 + 80 floats

static __device__ __forceinline__ ushort_t f2bf(float f) {
    unsigned int u = __float_as_uint(f);
    u += 0x7fffu + ((u >> 16) & 1u);     // RNE
    return (ushort_t)(u >> 16);
}
static __device__ __forceinline__ float bf2f(ushort_t h) {
    return __uint_as_float(((unsigned int)h) << 16);
}

// ---------------------------------------------------------------------------
// prep_xpad (once): copy x[256][9216] -> xp[256][XPITCH]. Dense both sides.
// ---------------------------------------------------------------------------
__global__ __launch_bounds__(256)
void prep_xpad_kernel(const float* __restrict__ x, float* __restrict__ xp)
{
    const int row = blockIdx.x;            // 0..255
    const int t   = threadIdx.x;           // 0..255
    const float* src = x  + (size_t)row * K_;
    float*       dst = xp + (size_t)row * XPITCH;
    #pragma unroll
    for (int v = 0; v < 9; ++v) {          // 9*256 = 2304 float4 = 9216 floats
        const int f4 = t + v * 256;
        *(float4*)(dst + (size_t)f4 * 4) = *(const float4*)(src + (size_t)f4 * 4);
    }
}

// ---------------------------------------------------------------------------
// prep_wpad (once): copy W[1152][1280] -> Wp[1152][WIPITCH]. Dense both sides.
// ---------------------------------------------------------------------------
__global__ __launch_bounds__(128)
void prep_wpad_kernel(const float* __restrict__ W, float* __restrict__ Wp)
{
    const int row = blockIdx.x;            // 0..1151 (i index)
    const int t   = threadIdx.x;           // 0..127
    const float* src = W  + (size_t)row * (J_ * DOUT_ * DIN_);   // 1280 floats
    float*       dst = Wp + (size_t)row * WIPITCH;
    #pragma unroll
    for (int v = 0; v < 3; ++v) {          // 320 float4 per row
        const int f4 = t + v * 128;
        if (f4 < 320)
            *(float4*)(dst + (size_t)f4 * 4) = *(const float4*)(src + (size_t)f4 * 4);
    }
}

// ---------------------------------------------------------------------------
// Round-21 s-GEMM: r5's sync-free kernel (PASSED, 141.7us) with ONE change:
// operands come from channel-de-aliased padded copies (xp, Wp). All math,
// lane mappings, Dekker splits, epilogue identical -> bit-identical output.
//   Theory: x lane stride 36,864 B = 144*256 B aliased every lane to ONE L2
//   channel; W's i/kstep strides (20*256 B, 80*256 B) cycled only 4 channels.
//   ~5.9M L2 accesses through ~2-4 channels/XCD at ~1/cyc = the invariant
//   ~35-40us wall seen in r0/r2/r3/r5. Padded pitches rotate channels.
// ---------------------------------------------------------------------------
__global__ __launch_bounds__(128)
void gemm_s_part_kernel(const float* __restrict__ xp, const float* __restrict__ Wp,
                        const float* __restrict__ blog,
                        float* __restrict__ pbuf, const int iter)
{
    const int tid  = threadIdx.x;          // 0..127
    const int blk  = blockIdx.x;           // 0..1279
    const int kb   = blk & 7;              // K-slice / XCD (perf-only heuristic)
    const int tile = blk >> 3;             // 0..159
    const int mb   = tile & 15;            // 0..15
    const int nt   = tile >> 4;            // 0..9
    const int lane = tid & 63;
    const int w    = tid >> 6;             // 0..1
    const int kc   = kb * 2 + w;           // 0..15: wave's k-chunk index

    __shared__ float   c_lds[144];         // c[i][nt] for this block's 144 i's
    __shared__ floatx4 part[2 * 64];

    if (iter > 0) {
        for (int r2 = tid; r2 < 144; r2 += 128) {
            const float* br = blog + (size_t)(kb * 144 + r2) * J_;
            float bv[J_];
            float mx = -1e30f;
            #pragma unroll
            for (int j = 0; j < J_; ++j) { bv[j] = br[j]; mx = fmaxf(mx, bv[j]); }
            float sum = 0.f;
            #pragma unroll
            for (int j = 0; j < J_; ++j) { bv[j] = __expf(bv[j] - mx); sum += bv[j]; }
            c_lds[r2] = bv[nt] / sum;
        }
        __syncthreads();
    }

    {
        const int r = lane & 15, q = lane >> 4;
        const float* ap = xp + (size_t)(mb * 16 + r) * XPITCH + kc * KCHUNK + 8 * q;
        // B row (j=nt, o=r); k-frag covers i = kc*72 + 4s + q, d=0..7
        const float* wp = Wp + (size_t)(kc * 72 + q) * WIPITCH + (nt * DOUT_ + r) * DIN_;
        const size_t wstep = (size_t)4 * WIPITCH;
        floatx4 acc = {0.f, 0.f, 0.f, 0.f};

        // 2-deep prefetch ring (fully unrolled loop -> static indices)
        float4 bxa0[2], bxa1[2], bw0[2], bw1[2];
        #pragma unroll
        for (int s = 0; s < 2; ++s) {
            bxa0[s] = *(const float4*)(ap + s * 32);
            bxa1[s] = *(const float4*)(ap + s * 32 + 4);
            bw0[s]  = *(const float4*)(wp + s * wstep);
            bw1[s]  = *(const float4*)(wp + s * wstep + 4);
        }
        #pragma unroll
        for (int s = 0; s < KSTEPS; ++s) {
            float4 xa0 = bxa0[s & 1], xa1 = bxa1[s & 1];
            float4 w0  = bw0[s & 1],  w1  = bw1[s & 1];
            if (s + 2 < KSTEPS) {
                bxa0[s & 1] = *(const float4*)(ap + (s + 2) * 32);
                bxa1[s & 1] = *(const float4*)(ap + (s + 2) * 32 + 4);
                bw0[s & 1]  = *(const float4*)(wp + (s + 2) * wstep);
                bw1[s & 1]  = *(const float4*)(wp + (s + 2) * wstep + 4);
            }
            float cs = (iter == 0) ? 0.1f : c_lds[w * 72 + 4 * s + q];
            float xv[8]  = {xa0.x, xa0.y, xa0.z, xa0.w, xa1.x, xa1.y, xa1.z, xa1.w};
            float wvv[8] = {w0.x, w0.y, w0.z, w0.w, w1.x, w1.y, w1.z, w1.w};
            bf16x8 ah, al, bh, bl;
            #pragma unroll
            for (int e = 0; e < 8; ++e) {
                float xe = xv[e];
                __bf16 h = (__bf16)xe;
                ah[e] = h;
                al[e] = (__bf16)(xe - (float)h);
                float pe = wvv[e] * cs;
                __bf16 g = (__bf16)pe;
                bh[e] = g;
                bl[e] = (__bf16)(pe - (float)g);
            }
            acc = __builtin_amdgcn_mfma_f32_16x16x32_bf16(ah, bh, acc, 0, 0, 0);
            acc = __builtin_amdgcn_mfma_f32_16x16x32_bf16(al, bh, acc, 0, 0, 0);
            acc = __builtin_amdgcn_mfma_f32_16x16x32_bf16(ah, bl, acc, 0, 0, 0);
        }
        part[w * 64 + lane] = acc;
    }
    __syncthreads();

    // ---- in-block pair-reduce -> plain store of 16x16 partial, exit ----
    const int row  = tid >> 3;             // 0..15 (b_local)
    const int col2 = (tid & 7) * 2;        // o pair base
    float2 v2;
    #pragma unroll
    for (int h = 0; h < 2; ++h) {
        const int o      = col2 + h;
        const int lane_c = ((row >> 2) << 4) | o;   // C/D: col=lane&15, row=quad*4+reg
        const int reg    = row & 3;
        ((float*)&v2)[h] = part[lane_c][reg] + part[64 + lane_c][reg];
    }
    *(float2*)(pbuf + (size_t)blk * 256 + row * 16 + col2) = v2;
}

// ---------------------------------------------------------------------------
// Stage 2: reduce 8 k-slice partials per tile + squash + emit (unchanged r5).
// ---------------------------------------------------------------------------
__global__ __launch_bounds__(256)
void reduce_squash_kernel(const float* __restrict__ pbuf, float* __restrict__ s_out,
                          ushort_t* __restrict__ Sbt_hi, ushort_t* __restrict__ Sbt_lo,
                          const int iter)
{
    const int tile = blockIdx.x;           // 0..159 (same mapping as stage 1)
    const int mb   = tile & 15;
    const int nt   = tile >> 4;
    const int t    = threadIdx.x;          // 0..255
    const int row  = t >> 4;               // 0..15 (b_local)
    const int o    = t & 15;               // 0..15

    const float* pb = pbuf + (size_t)tile * 8 * 256 + row * 16 + o;
    float v = 0.f;
    #pragma unroll
    for (int u = 0; u < 8; ++u)
        v += pb[u * 256];

    float sq = v * v;
    #pragma unroll
    for (int off = 1; off < 16; off <<= 1)  // 16 consecutive lanes = one b row
        sq += __shfl_xor(sq, off, 16);
    float l2 = sqrtf(sq);
    float val = v * (l2 / (1.f + sq));
    const int b  = mb * 16 + row;
    const int jo = nt * 16 + o;
    if (iter == 2) {
        s_out[(size_t)b * N_ + jo] = val;
    } else {
        ushort_t hi = f2bf(val);
        Sbt_hi[(size_t)jo * B_ + b] = hi;
        Sbt_lo[(size_t)jo * B_ + b] = f2bf(val - bf2f(hi));
    }
}

// ---------------------------------------------------------------------------
// b-update GEMM (unchanged r5 — reads original x/W; its access patterns are
// dense/channel-spread: x along k in full 64B lines, Sbt contiguous).
// ---------------------------------------------------------------------------
__global__ __launch_bounds__(256)
void gemm_bupd_kernel(const float* __restrict__ x,
                      const ushort_t* __restrict__ Sbt_hi, const ushort_t* __restrict__ Sbt_lo,
                      const float* __restrict__ W, float* __restrict__ blog,
                      const int first)
{
    // bijective remap: XCD (blk&7) gets wv in [xcd*360, xcd*360+360) -> mt
    // in [xcd*72, xcd*72+72) contiguous (720 blocks, 720%8==0).
    int wv   = (blockIdx.x & 7) * 360 + (blockIdx.x >> 3) * 4 + (threadIdx.x >> 6);
    int lane = threadIdx.x & 63;
    int mt = wv / 5;                                  // 0..575
    int jp = wv - mt * 5;                             // j-pair: j0=2jp, j1=2jp+1
    int j0 = jp * 2, j1 = jp * 2 + 1;
    int r = lane & 15, q = lane >> 4;
    const float* xp = x + (size_t)(8 * q) * K_ + (mt * 16 + r);   // + (s*32+e)*K_
    size_t b0off = (size_t)(j0 * 16 + r) * B_ + 8 * q;
    size_t b1off = (size_t)(j1 * 16 + r) * B_ + 8 * q;
    floatx4 acc0 = {0.f, 0.f, 0.f, 0.f};
    floatx4 acc1 = {0.f, 0.f, 0.f, 0.f};

    float xcur[8], xnxt[8];
    #pragma unroll
    for (int e = 0; e < 8; ++e) xcur[e] = xp[(size_t)e * K_];
    #pragma unroll
    for (int s = 0; s < B_ / 32; ++s) {
        if (s + 1 < B_ / 32) {               // prefetch next step's x column slice
            #pragma unroll
            for (int e = 0; e < 8; ++e)
                xnxt[e] = xp[(size_t)((s + 1) * 32 + e) * K_];
        }
        bf16x8 ah, al;
        #pragma unroll
        for (int e = 0; e < 8; ++e) {
            float v = xcur[e];
            __bf16 h = (__bf16)v;
            ah[e] = h;
            al[e] = (__bf16)(v - (float)h);
        }
        bf16x8 bh0 = *(const bf16x8*)(Sbt_hi + b0off + s * 32);
        bf16x8 bl0 = *(const bf16x8*)(Sbt_lo + b0off + s * 32);
        bf16x8 bh1 = *(const bf16x8*)(Sbt_hi + b1off + s * 32);
        bf16x8 bl1 = *(const bf16x8*)(Sbt_lo + b1off + s * 32);
        acc0 = __builtin_amdgcn_mfma_f32_16x16x32_bf16(ah, bh0, acc0, 0, 0, 0);
        acc0 = __builtin_amdgcn_mfma_f32_16x16x32_bf16(al, bh0, acc0, 0, 0, 0);
        acc0 = __builtin_amdgcn_mfma_f32_16x16x32_bf16(ah, bl0, acc0, 0, 0, 0);
        acc1 = __builtin_amdgcn_mfma_f32_16x16x32_bf16(ah, bh1, acc1, 0, 0, 0);
        acc1 = __builtin_amdgcn_mfma_f32_16x16x32_bf16(al, bh1, acc1, 0, 0, 0);
        acc1 = __builtin_amdgcn_mfma_f32_16x16x32_bf16(ah, bl1, acc1, 0, 0, 0);
        #pragma unroll
        for (int e = 0; e < 8; ++e) xcur[e] = xnxt[e];
    }
    // rows q*4+reg -> i = mt*2 + (q>>1), d = (q&1)*4 + reg; col -> o = lane&15
    int i  = mt * 2 + (q >> 1);
    int d0 = (q & 1) * 4;
    int o  = lane & 15;
    int iw = mt * 2 + (lane >> 5);
    {
        const float4 w4 = *(const float4*)(W + ((((size_t)i * J_ + j0) * DOUT_ + o) * DIN_ + d0));
        float val = acc0[0] * w4.x + acc0[1] * w4.y + acc0[2] * w4.z + acc0[3] * w4.w;
        #pragma unroll
        for (int off = 1; off < 32; off <<= 1)
            val += __shfl_xor(val, off, 32);
        if ((lane & 31) == 0) {
            float* dst = blog + (size_t)iw * J_ + j0;
            if (first) *dst = val; else *dst += val;
        }
    }
    {
        const float4 w4 = *(const float4*)(W + ((((size_t)i * J_ + j1) * DOUT_ + o) * DIN_ + d0));
        float val = acc1[0] * w4.x + acc1[1] * w4.y + acc1[2] * w4.z + acc1[3] * w4.w;
        #pragma unroll
        for (int off = 1; off < 32; off <<= 1)
            val += __shfl_xor(val, off, 32);
        if ((lane & 31) == 0) {
            float* dst = blog + (size_t)iw * J_ + j1;
            if (first) *dst = val; else *dst += val;
        }
    }
}

// ---------------------------------------------------------------------------
extern "C" void kernel_launch(void* const* d_in, const int* in_sizes, int n_in,
                              void* d_out, int out_size, void* d_ws, size_t ws_size,
                              hipStream_t stream)
{
    const float* x = (const float*)d_in[0];   // [B, I, DIN]
    const float* W = (const float*)d_in[1];   // [I, J, DOUT, DIN]
    float* s_out = (float*)d_out;             // [B, J, DOUT]

    char* ws = (char*)d_ws;
    ushort_t* Sbt_hi = (ushort_t*)(ws);                 //    81,920 B
    ushort_t* Sbt_lo = (ushort_t*)(ws + 81920);         //    81,920 B
    float*    blog   = (float*)   (ws + 163840);        //    46,080 B
    float*    pbuf   = (float*)   (ws + 262144);        // 1,310,720 B
    float*    xpad   = (float*)   (ws + 1572864);       // 9,519,104 B (256*9296*4)
    float*    Wpad   = (float*)   (ws + 11091968);      // 6,266,880 B (1152*1360*4)
                                                        // total ~17.4 MB

    prep_xpad_kernel<<<256, 256, 0, stream>>>(x, xpad);
    prep_wpad_kernel<<<1152, 128, 0, stream>>>(W, Wpad);

    for (int it = 0; it < 3; ++it) {
        gemm_s_part_kernel<<<1280, 128, 0, stream>>>(xpad, Wpad, blog, pbuf, it);
        reduce_squash_kernel<<<160, 256, 0, stream>>>(pbuf, s_out,
                                                      Sbt_hi, Sbt_lo, it);
        if (it < 2)
            gemm_bupd_kernel<<<720, 256, 0, stream>>>(x, Sbt_hi, Sbt_lo,
                                                      W, blog, it == 0 ? 1 : 0);
    }
}

// Round 7
// 135.938 us; speedup vs baseline: 1.0551x; 1.0551x over previous
//
#include <hip/hip_runtime.h>
#include <math.h>

typedef unsigned short ushort_t;
typedef __attribute__((ext_vector_type(8))) __bf16 bf16x8;
typedef __attribute__((ext_vector_type(4))) float floatx4;

#define B_    256
#define I_    1152
#define J_    10
#define DIN_  8
#define DOUT_ 16
#define K_    (I_*DIN_)     // 9216
#define N_    (J_*DOUT_)    // 160
#define KSPLIT 16           // total split-K per output tile
#define KCHUNK (K_/KSPLIT)  // 576 (72 i's per wave)
#define KSTEPS (KCHUNK/32)  // 18

// Packed-chunk stride: one (mb|nt, kc) chunk = 18 steps * 2 planes * 1KB
// = 36,864 B; pad +1KB -> 37 KB (odd multiple of 1KB) so concurrent
// streams land on different L2 channel phases. Unit below = 16 B.
#define CHUNK16 2368        // 37*1024/16

static __device__ __forceinline__ ushort_t f2bf(float f) {
    unsigned int u = __float_as_uint(f);
    u += 0x7fffu + ((u >> 16) & 1u);     // RNE
    return (ushort_t)(u >> 16);
}
static __device__ __forceinline__ float bf2f(ushort_t h) {
    return __uint_as_float(((unsigned int)h) << 16);
}

// ---------------------------------------------------------------------------
// prep_xpack (once): x -> fragment-major Dekker bf16 hi/lo planes.
// Thread = 8 consecutive src floats (coalesced read); writes the two 16-B
// lane-fragments (hi, lo) to the packed layout. Split values bit-identical
// to what the r5 kernel computed in-loop.
// Layout (16B units): (mb*16+kc)*CHUNK16 + (s*2+p)*64 + q*16 + r.
// ---------------------------------------------------------------------------
__global__ __launch_bounds__(256)
void prep_xpack_kernel(const float* __restrict__ x, ushort_t* __restrict__ xPk)
{
    const int gid = blockIdx.x * 256 + threadIdx.x;   // 0..294911
    const int f   = gid * 8;
    const int row = f / K_;                 // b: 0..255
    const int kk  = f - row * K_;
    const int kc  = kk / KCHUNK;            // 0..15
    const int t   = kk - kc * KCHUNK;
    const int s   = t >> 5;                 // 0..17
    const int q   = (t & 31) >> 3;          // 0..3
    const int mb  = row >> 4, r = row & 15;

    const float* src = x + (size_t)f;
    bf16x8 h8, l8;
    #pragma unroll
    for (int e = 0; e < 8; ++e) {
        float v = src[e];
        __bf16 h = (__bf16)v;
        h8[e] = h;
        l8[e] = (__bf16)(v - (float)h);
    }
    bf16x8* dst = (bf16x8*)xPk + (size_t)(mb * 16 + kc) * CHUNK16 + s * 128 + q * 16 + r;
    dst[0]  = h8;       // plane 0 (hi)
    dst[64] = l8;       // plane 1 (lo)
}

// ---------------------------------------------------------------------------
// prep_wpack (once): W -> fragment-major fp32 (exact copy, permuted).
// Thread = 1 src float4 (coalesced read), scatter write.
// Layout (float4 units): (nt*16+kc)*CHUNK16 + (s*2+p)*64 + q*16 + r.
// ---------------------------------------------------------------------------
__global__ __launch_bounds__(256)
void prep_wpack_kernel(const float* __restrict__ W, float* __restrict__ wPk)
{
    const int gid = blockIdx.x * 256 + threadIdx.x;   // 0..368639
    const int f   = gid * 4;
    const int i   = f / 1280;               // 0..1151
    const int rem = f - i * 1280;
    const int no  = rem >> 3;               // nt*16 + r
    const int p   = (rem >> 2) & 1;
    const int nt  = no >> 4, r = no & 15;
    const int kc  = i / 72;
    const int m   = i - kc * 72;
    const int s   = m >> 2, q = m & 3;

    float4 v = *(const float4*)(W + (size_t)f);
    ((float4*)wPk)[(size_t)(nt * 16 + kc) * CHUNK16 + (s * 2 + p) * 64 + q * 16 + r] = v;
}

// ---------------------------------------------------------------------------
// Round-22 s-GEMM: r5's sync-free kernel (PASSED, 141.7us) with ONE change:
// all K-loop loads come from fragment-major packed operands -> each load is
// one contiguous 1KB burst (base + lane*16B, 16 full 64B lines, no split
// lines). Theory: the invariant ~35us across r0/r2/r3/r5/r6 is L2 request-
// rate: scattered fragments cost ~128 line-requests per wave-step (~5.9M
// total); packed costs 64 full-line requests (~2.3M) uniformly striped.
// x planes ARE the Dekker splits (prep, bit-identical); W fp32 packed, cs
// multiply + split in-loop unchanged -> output bit-identical to r5.
// ---------------------------------------------------------------------------
__global__ __launch_bounds__(128)
void gemm_s_part_kernel(const ushort_t* __restrict__ xPk, const float* __restrict__ wPk,
                        const float* __restrict__ blog,
                        float* __restrict__ pbuf, const int iter)
{
    const int tid  = threadIdx.x;          // 0..127
    const int blk  = blockIdx.x;           // 0..1279
    const int kb   = blk & 7;              // K-slice / XCD (perf-only heuristic)
    const int tile = blk >> 3;             // 0..159
    const int mb   = tile & 15;            // 0..15
    const int nt   = tile >> 4;            // 0..9
    const int lane = tid & 63;
    const int w    = tid >> 6;             // 0..1
    const int kc   = kb * 2 + w;           // 0..15: wave's k-chunk index

    __shared__ float   c_lds[144];         // c[i][nt] for this block's 144 i's
    __shared__ floatx4 part[2 * 64];

    if (iter > 0) {
        for (int r2 = tid; r2 < 144; r2 += 128) {
            const float* br = blog + (size_t)(kb * 144 + r2) * J_;
            float bv[J_];
            float mx = -1e30f;
            #pragma unroll
            for (int j = 0; j < J_; ++j) { bv[j] = br[j]; mx = fmaxf(mx, bv[j]); }
            float sum = 0.f;
            #pragma unroll
            for (int j = 0; j < J_; ++j) { bv[j] = __expf(bv[j] - mx); sum += bv[j]; }
            c_lds[r2] = bv[nt] / sum;
        }
        __syncthreads();
    }

    {
        const int q = lane >> 4;
        const bf16x8* xp = (const bf16x8*)xPk + (size_t)(mb * 16 + kc) * CHUNK16 + lane;
        const float4* wp = (const float4*)wPk + (size_t)(nt * 16 + kc) * CHUNK16 + lane;
        floatx4 acc = {0.f, 0.f, 0.f, 0.f};

        // 2-deep prefetch ring (fully unrolled loop -> static indices)
        bf16x8 rah[2], ral[2];
        float4 rw0[2], rw1[2];
        #pragma unroll
        for (int s = 0; s < 2; ++s) {
            rah[s] = xp[s * 128];
            ral[s] = xp[s * 128 + 64];
            rw0[s] = wp[s * 128];
            rw1[s] = wp[s * 128 + 64];
        }
        #pragma unroll
        for (int s = 0; s < KSTEPS; ++s) {
            bf16x8 ah = rah[s & 1], al = ral[s & 1];
            float4 w0 = rw0[s & 1], w1 = rw1[s & 1];
            if (s + 2 < KSTEPS) {
                rah[s & 1] = xp[(s + 2) * 128];
                ral[s & 1] = xp[(s + 2) * 128 + 64];
                rw0[s & 1] = wp[(s + 2) * 128];
                rw1[s & 1] = wp[(s + 2) * 128 + 64];
            }
            float cs = (iter == 0) ? 0.1f : c_lds[w * 72 + 4 * s + q];
            float wvv[8] = {w0.x, w0.y, w0.z, w0.w, w1.x, w1.y, w1.z, w1.w};
            bf16x8 bh, bl;
            #pragma unroll
            for (int e = 0; e < 8; ++e) {
                float pe = wvv[e] * cs;
                __bf16 g = (__bf16)pe;
                bh[e] = g;
                bl[e] = (__bf16)(pe - (float)g);
            }
            acc = __builtin_amdgcn_mfma_f32_16x16x32_bf16(ah, bh, acc, 0, 0, 0);
            acc = __builtin_amdgcn_mfma_f32_16x16x32_bf16(al, bh, acc, 0, 0, 0);
            acc = __builtin_amdgcn_mfma_f32_16x16x32_bf16(ah, bl, acc, 0, 0, 0);
        }
        part[w * 64 + lane] = acc;
    }
    __syncthreads();

    // ---- in-block pair-reduce -> plain store of 16x16 partial, exit ----
    const int row  = tid >> 3;             // 0..15 (b_local)
    const int col2 = (tid & 7) * 2;        // o pair base
    float2 v2;
    #pragma unroll
    for (int h = 0; h < 2; ++h) {
        const int o      = col2 + h;
        const int lane_c = ((row >> 2) << 4) | o;   // C/D: col=lane&15, row=quad*4+reg
        const int reg    = row & 3;
        ((float*)&v2)[h] = part[lane_c][reg] + part[64 + lane_c][reg];
    }
    *(float2*)(pbuf + (size_t)blk * 256 + row * 16 + col2) = v2;
}

// ---------------------------------------------------------------------------
// Stage 2: reduce 8 k-slice partials per tile + squash + emit (unchanged r5).
// ---------------------------------------------------------------------------
__global__ __launch_bounds__(256)
void reduce_squash_kernel(const float* __restrict__ pbuf, float* __restrict__ s_out,
                          ushort_t* __restrict__ Sbt_hi, ushort_t* __restrict__ Sbt_lo,
                          const int iter)
{
    const int tile = blockIdx.x;           // 0..159 (same mapping as stage 1)
    const int mb   = tile & 15;
    const int nt   = tile >> 4;
    const int t    = threadIdx.x;          // 0..255
    const int row  = t >> 4;               // 0..15 (b_local)
    const int o    = t & 15;               // 0..15

    const float* pb = pbuf + (size_t)tile * 8 * 256 + row * 16 + o;
    float v = 0.f;
    #pragma unroll
    for (int u = 0; u < 8; ++u)
        v += pb[u * 256];

    float sq = v * v;
    #pragma unroll
    for (int off = 1; off < 16; off <<= 1)  // 16 consecutive lanes = one b row
        sq += __shfl_xor(sq, off, 16);
    float l2 = sqrtf(sq);
    float val = v * (l2 / (1.f + sq));
    const int b  = mb * 16 + row;
    const int jo = nt * 16 + o;
    if (iter == 2) {
        s_out[(size_t)b * N_ + jo] = val;
    } else {
        ushort_t hi = f2bf(val);
        Sbt_hi[(size_t)jo * B_ + b] = hi;
        Sbt_lo[(size_t)jo * B_ + b] = f2bf(val - bf2f(hi));
    }
}

// ---------------------------------------------------------------------------
// b-update GEMM (unchanged r5 — reads original x/W; its access patterns are
// dense/channel-spread: x along k in full 64B lines, Sbt contiguous).
// ---------------------------------------------------------------------------
__global__ __launch_bounds__(256)
void gemm_bupd_kernel(const float* __restrict__ x,
                      const ushort_t* __restrict__ Sbt_hi, const ushort_t* __restrict__ Sbt_lo,
                      const float* __restrict__ W, float* __restrict__ blog,
                      const int first)
{
    // bijective remap: XCD (blk&7) gets wv in [xcd*360, xcd*360+360) -> mt
    // in [xcd*72, xcd*72+72) contiguous (720 blocks, 720%8==0).
    int wv   = (blockIdx.x & 7) * 360 + (blockIdx.x >> 3) * 4 + (threadIdx.x >> 6);
    int lane = threadIdx.x & 63;
    int mt = wv / 5;                                  // 0..575
    int jp = wv - mt * 5;                             // j-pair: j0=2jp, j1=2jp+1
    int j0 = jp * 2, j1 = jp * 2 + 1;
    int r = lane & 15, q = lane >> 4;
    const float* xp = x + (size_t)(8 * q) * K_ + (mt * 16 + r);   // + (s*32+e)*K_
    size_t b0off = (size_t)(j0 * 16 + r) * B_ + 8 * q;
    size_t b1off = (size_t)(j1 * 16 + r) * B_ + 8 * q;
    floatx4 acc0 = {0.f, 0.f, 0.f, 0.f};
    floatx4 acc1 = {0.f, 0.f, 0.f, 0.f};

    float xcur[8], xnxt[8];
    #pragma unroll
    for (int e = 0; e < 8; ++e) xcur[e] = xp[(size_t)e * K_];
    #pragma unroll
    for (int s = 0; s < B_ / 32; ++s) {
        if (s + 1 < B_ / 32) {               // prefetch next step's x column slice
            #pragma unroll
            for (int e = 0; e < 8; ++e)
                xnxt[e] = xp[(size_t)((s + 1) * 32 + e) * K_];
        }
        bf16x8 ah, al;
        #pragma unroll
        for (int e = 0; e < 8; ++e) {
            float v = xcur[e];
            __bf16 h = (__bf16)v;
            ah[e] = h;
            al[e] = (__bf16)(v - (float)h);
        }
        bf16x8 bh0 = *(const bf16x8*)(Sbt_hi + b0off + s * 32);
        bf16x8 bl0 = *(const bf16x8*)(Sbt_lo + b0off + s * 32);
        bf16x8 bh1 = *(const bf16x8*)(Sbt_hi + b1off + s * 32);
        bf16x8 bl1 = *(const bf16x8*)(Sbt_lo + b1off + s * 32);
        acc0 = __builtin_amdgcn_mfma_f32_16x16x32_bf16(ah, bh0, acc0, 0, 0, 0);
        acc0 = __builtin_amdgcn_mfma_f32_16x16x32_bf16(al, bh0, acc0, 0, 0, 0);
        acc0 = __builtin_amdgcn_mfma_f32_16x16x32_bf16(ah, bl0, acc0, 0, 0, 0);
        acc1 = __builtin_amdgcn_mfma_f32_16x16x32_bf16(ah, bh1, acc1, 0, 0, 0);
        acc1 = __builtin_amdgcn_mfma_f32_16x16x32_bf16(al, bh1, acc1, 0, 0, 0);
        acc1 = __builtin_amdgcn_mfma_f32_16x16x32_bf16(ah, bl1, acc1, 0, 0, 0);
        #pragma unroll
        for (int e = 0; e < 8; ++e) xcur[e] = xnxt[e];
    }
    // rows q*4+reg -> i = mt*2 + (q>>1), d = (q&1)*4 + reg; col -> o = lane&15
    int i  = mt * 2 + (q >> 1);
    int d0 = (q & 1) * 4;
    int o  = lane & 15;
    int iw = mt * 2 + (lane >> 5);
    {
        const float4 w4 = *(const float4*)(W + ((((size_t)i * J_ + j0) * DOUT_ + o) * DIN_ + d0));
        float val = acc0[0] * w4.x + acc0[1] * w4.y + acc0[2] * w4.z + acc0[3] * w4.w;
        #pragma unroll
        for (int off = 1; off < 32; off <<= 1)
            val += __shfl_xor(val, off, 32);
        if ((lane & 31) == 0) {
            float* dst = blog + (size_t)iw * J_ + j0;
            if (first) *dst = val; else *dst += val;
        }
    }
    {
        const float4 w4 = *(const float4*)(W + ((((size_t)i * J_ + j1) * DOUT_ + o) * DIN_ + d0));
        float val = acc1[0] * w4.x + acc1[1] * w4.y + acc1[2] * w4.z + acc1[3] * w4.w;
        #pragma unroll
        for (int off = 1; off < 32; off <<= 1)
            val += __shfl_xor(val, off, 32);
        if ((lane & 31) == 0) {
            float* dst = blog + (size_t)iw * J_ + j1;
            if (first) *dst = val; else *dst += val;
        }
    }
}

// ---------------------------------------------------------------------------
extern "C" void kernel_launch(void* const* d_in, const int* in_sizes, int n_in,
                              void* d_out, int out_size, void* d_ws, size_t ws_size,
                              hipStream_t stream)
{
    const float* x = (const float*)d_in[0];   // [B, I, DIN]
    const float* W = (const float*)d_in[1];   // [I, J, DOUT, DIN]
    float* s_out = (float*)d_out;             // [B, J, DOUT]

    char* ws = (char*)d_ws;
    ushort_t* Sbt_hi = (ushort_t*)(ws);                 //    81,920 B
    ushort_t* Sbt_lo = (ushort_t*)(ws + 81920);         //    81,920 B
    float*    blog   = (float*)   (ws + 163840);        //    46,080 B
    float*    pbuf   = (float*)   (ws + 262144);        // 1,310,720 B
    ushort_t* xPk    = (ushort_t*)(ws + 1572864);       // 9,699,328 B (256 chunks * 37KB)
    float*    wPk    = (float*)   (ws + 11272192);      // 6,062,080 B (160 chunks * 37KB)
                                                        // total ~17.3 MB

    prep_xpack_kernel<<<1152, 256, 0, stream>>>(x, xPk);
    prep_wpack_kernel<<<1440, 256, 0, stream>>>(W, wPk);

    for (int it = 0; it < 3; ++it) {
        gemm_s_part_kernel<<<1280, 128, 0, stream>>>(xPk, wPk, blog, pbuf, it);
        reduce_squash_kernel<<<160, 256, 0, stream>>>(pbuf, s_out,
                                                      Sbt_hi, Sbt_lo, it);
        if (it < 2)
            gemm_bupd_kernel<<<720, 256, 0, stream>>>(x, Sbt_hi, Sbt_lo,
                                                      W, blog, it == 0 ? 1 : 0);
    }
}